// Round 4
// baseline (686.444 us; speedup 1.0000x reference)
//
#include <hip/hip_runtime.h>

typedef unsigned short u16;
typedef __attribute__((ext_vector_type(8))) short bf8v;   // 8 bf16 = 4 VGPRs
typedef __attribute__((ext_vector_type(4))) float f4v;

#define DEV static __device__ __forceinline__

DEV float bf2f(u16 u){ unsigned x = ((unsigned)u) << 16; float f; __builtin_memcpy(&f, &x, 4); return f; }
DEV u16 f2bf(float f){ unsigned x; __builtin_memcpy(&x, &f, 4); x += 0x7fff + ((x >> 16) & 1); return (u16)(x >> 16); }

DEV void async16(const void* g, void* l){
  __builtin_amdgcn_global_load_lds((const __attribute__((address_space(1))) unsigned*)g,
                                   (__attribute__((address_space(3))) unsigned*)l, 16, 0, 0);
}

// ---------------------------------------------------------------------------
// fp32 -> bf16 conversion, 4 elements/thread.
// ---------------------------------------------------------------------------
__global__ __launch_bounds__(256) void f2b_k(const float* __restrict__ src,
                                             u16* __restrict__ dst)
{
  const long i = ((long)blockIdx.x * 256 + threadIdx.x) * 4;
  const float4 v = *(const float4*)(src + i);
  ushort4 o;
  o.x = f2bf(v.x); o.y = f2bf(v.y); o.z = f2bf(v.z); o.w = f2bf(v.w);
  *(ushort4*)(dst + i) = o;
}

// three weights -> one contiguous [6144,2048] bf16 buffer
__global__ __launch_bounds__(256) void f2b3_k(const float* __restrict__ a,
                                              const float* __restrict__ b,
                                              const float* __restrict__ c,
                                              u16* __restrict__ dst)
{
  const int bx = blockIdx.x;                       // 0..12287
  const float* s = bx < 4096 ? a : (bx < 8192 ? b : c);
  const long soff = ((long)(bx & 4095) * 256 + threadIdx.x) * 4;
  const long doff = ((long)bx * 256 + threadIdx.x) * 4;
  const float4 v = *(const float4*)(s + soff);
  ushort4 o;
  o.x = f2bf(v.x); o.y = f2bf(v.y); o.z = f2bf(v.z); o.w = f2bf(v.w);
  *(ushort4*)(dst + doff) = o;
}

// ---------------------------------------------------------------------------
// GEMM: C[M,N] = A[M,K] * B[N,K]^T, bf16 in, fp32 accum. K=2048, M=4096.
// 128x128 tile, BK=32, 4 waves (2x2 of 64x64). Identity LDS chunk layout:
// chunk p (16B) holds row=(p>>8)*64+((p>>6)&3)*16+(p&15), kc=((p>>4)&3)*8,
// so frag reads are chunk = grp*64 + lane (stride-1 b128, conflict-free).
// SINGLE-BARRIER double-buffered K-loop: prefetch tile k+1 right after the
// barrier; barrier k+1 drains it after a full compute-block in flight.
// mode 0: C0 bf16 row-major [M,2048]
// mode 1: C0 <- V-transpose [bh,d,s]
// mode 2: Cf fp32 row-major (final output)
// mode 3: fused QKV (N=6144): sec0->C0 (q), sec1->C1 (k), sec2->C2 (v transp)
// ---------------------------------------------------------------------------
constexpr int KDIM = 2048;

DEV int rowof(int c){ int grp = c >> 6; return (grp >> 2) * 64 + (grp & 3) * 16 + (c & 15); }

__global__ __launch_bounds__(256) void gemm_bt(const u16* __restrict__ A,
                                               const u16* __restrict__ B,
                                               u16* __restrict__ C0,
                                               u16* __restrict__ C1,
                                               u16* __restrict__ C2,
                                               float* __restrict__ Cf, int mode)
{
  __shared__ __align__(16) u16 As[2][128 * 32];   // 2 x 8 KB
  __shared__ __align__(16) u16 Bs[2][128 * 32];   // 2 x 8 KB
  const int tid = threadIdx.x;
  const int w = tid >> 6, lane = tid & 63;
  const int ln = lane & 15, quad = lane >> 4;
  const int wm = (w >> 1) << 6, wn = (w & 1) << 6;
  const long m0 = (long)blockIdx.y << 7, n0 = (long)blockIdx.x << 7;

  f4v acc[4][4] = {};

  const int c0 = tid, c1 = 256 + tid;
  const u16* ga0 = A + (m0 + rowof(c0)) * KDIM + ((c0 >> 4) & 3) * 8;
  const u16* ga1 = A + (m0 + rowof(c1)) * KDIM + ((c1 >> 4) & 3) * 8;
  const u16* gb0 = B + (n0 + rowof(c0)) * KDIM + ((c0 >> 4) & 3) * 8;
  const u16* gb1 = B + (n0 + rowof(c1)) * KDIM + ((c1 >> 4) & 3) * 8;
  const int lo = w * 1024;                    // wave-uniform base; HW adds lane*16

  // prologue: stage tile 0 into buffer 0
  async16(ga0, (char*)As[0] + lo);
  async16(ga1, (char*)As[0] + 4096 + lo);
  async16(gb0, (char*)Bs[0] + lo);
  async16(gb1, (char*)Bs[0] + 4096 + lo);

#pragma unroll 2
  for (int it = 0; it < KDIM / 32; ++it) {
    __syncthreads();                          // tile it resident; prev buf free
    if (it + 1 < KDIM / 32) {                 // prefetch tile it+1 (in flight
      const int bi = (it + 1) & 1;            //  across the whole compute below)
      const int k0 = (it + 1) * 32;
      async16(ga0 + k0, (char*)As[bi] + lo);
      async16(ga1 + k0, (char*)As[bi] + 4096 + lo);
      async16(gb0 + k0, (char*)Bs[bi] + lo);
      async16(gb1 + k0, (char*)Bs[bi] + 4096 + lo);
    }
    const u16* Ab = As[it & 1];
    const u16* Bb = Bs[it & 1];
    bf8v a[4], b[4];
#pragma unroll
    for (int i = 0; i < 4; i++) a[i] = *(const bf8v*)&Ab[(((w >> 1) * 4 + i) * 64 + lane) * 8];
#pragma unroll
    for (int j = 0; j < 4; j++) b[j] = *(const bf8v*)&Bb[(((w & 1) * 4 + j) * 64 + lane) * 8];
#pragma unroll
    for (int i = 0; i < 4; i++)
#pragma unroll
      for (int j = 0; j < 4; j++)
        acc[i][j] = __builtin_amdgcn_mfma_f32_16x16x32_bf16(a[i], b[j], acc[i][j], 0, 0, 0);
  }

  // epilogue: D row = quad*4+reg (m), col = ln (n)
#pragma unroll
  for (int i = 0; i < 4; i++) {
    const long mrow = m0 + wm + i * 16 + quad * 4;
#pragma unroll
    for (int j = 0; j < 4; j++) {
      const long ncol = n0 + wn + j * 16 + ln;
#pragma unroll
      for (int r = 0; r < 4; r++) {
        const float fv = acc[i][j][r];
        const long m = mrow + r;
        if (mode == 0) {
          C0[m * 2048 + ncol] = f2bf(fv);
        } else if (mode == 2) {
          Cf[m * 2048 + ncol] = fv;
        } else if (mode == 1) {
          const long s = m & 2047, bb = m >> 11;
          const long hh = ncol >> 7, dc = ncol & 127;
          C0[((bb * 16 + hh) * 128 + dc) * 2048 + s] = f2bf(fv);
        } else {             // mode 3: fused QKV, sec uniform per block
          const int sec = (int)(n0 >> 11);
          const long nc = ncol & 2047;
          if (sec == 0)      C0[m * 2048 + nc] = f2bf(fv);
          else if (sec == 1) C1[m * 2048 + nc] = f2bf(fv);
          else {
            const long s = m & 2047, bb = m >> 11;
            const long hh = nc >> 7, dc = nc & 127;
            C2[((bb * 16 + hh) * 128 + dc) * 2048 + s] = f2bf(fv);
          }
        }
      }
    }
  }
}

// ---------------------------------------------------------------------------
// RoPE in place on q and k (bf16 [4096, 16*128]); cos/sin fp32 [2048,128].
// ---------------------------------------------------------------------------
__global__ __launch_bounds__(256) void rope2_k(u16* __restrict__ qb,
                                               u16* __restrict__ kb,
                                               const float* __restrict__ cs,
                                               const float* __restrict__ sn)
{
  const long idx = (long)blockIdx.x * 256 + threadIdx.x;   // [0, 2*4194304)
  u16* t = (idx >= 4194304) ? kb : qb;
  const long i2 = idx & 4194303;
  const long m = i2 >> 10;
  const int rest = (int)(i2 & 1023);
  const int h = rest >> 6, d = rest & 63;
  const int s = (int)(m & 2047);
  const long base = m * 2048 + h * 128 + d;
  const float a  = bf2f(t[base]), b = bf2f(t[base + 64]);
  const float c1 = cs[s * 128 + d],      s1 = sn[s * 128 + d];
  const float c2 = cs[s * 128 + d + 64], s2 = sn[s * 128 + d + 64];
  t[base]      = f2bf(a * c1 - b * s1);
  t[base + 64] = f2bf(b * c2 + a * s2);
}

// ---------------------------------------------------------------------------
// Flash attention (causal), double-buffered K/V staging, ONE barrier/iter.
// Block = 4 waves; wave w owns 16 q-rows. qt reversed (longest first).
// Identity LDS chunk layouts (conflict-free stride-1 b128 reads):
//   K chunk p: row kj = (p>>8)*16 + (p&15), d-off = ((p>>6)&3)*32 + ((p>>4)&3)*8
//   V chunk p: d = (p>>7)*16 + (p&15), k-off = ((p>>6)&1)*32 + ((p>>4)&3)*8
// ---------------------------------------------------------------------------
__global__ __launch_bounds__(256) void attn_k(const u16* __restrict__ q,
                                              const u16* __restrict__ k,
                                              const u16* __restrict__ vt,
                                              u16* __restrict__ ao)
{
  __shared__ __align__(16) u16 Ks[2][64 * 128];   // 2 x 16 KB
  __shared__ __align__(16) u16 Vs[2][64 * 128];   // 2 x 16 KB
  __shared__ __align__(16) u16 Ps[4 * 16 * 72];   // per-wave P, stride 72
  const int qt = 31 - blockIdx.x;                 // longest blocks first
  const int bh = blockIdx.y;
  const int b = bh >> 4, h = bh & 15;
  const int tid = threadIdx.x;
  const int w = tid >> 6, lane = tid & 63;
  const int ln = lane & 15, quad = lane >> 4;
  const int q0 = qt << 6;

  const u16* kbase[4]; const u16* vbase[4];
#pragma unroll
  for (int it = 0; it < 4; it++) {
    const int p = it * 256 + tid;
    { const int jt = p >> 8, dt = (p >> 6) & 3, qq = (p >> 4) & 3, l = p & 15;
      kbase[it] = k + ((long)(b * 2048 + jt * 16 + l)) * 2048 + h * 128 + dt * 32 + qq * 8; }
    { const int nt = p >> 7, k2 = (p >> 6) & 1, qq = (p >> 4) & 3, l = p & 15;
      vbase[it] = vt + ((long)(bh * 128 + nt * 16 + l)) * 2048 + k2 * 32 + qq * 8; }
  }

  // Q fragments (A operand: m = ln, k = quad*8+j per 32-chunk)
  bf8v aq[4];
  {
    const u16* qp = q + ((long)(b * 2048 + q0 + w * 16 + ln)) * 2048 + h * 128;
#pragma unroll
    for (int dt = 0; dt < 4; ++dt) aq[dt] = *(const bf8v*)(qp + dt * 32 + quad * 8);
  }
  f4v O[8] = {};
  float m_run[4] = {-1e30f, -1e30f, -1e30f, -1e30f};
  float l_run[4] = {0.f, 0.f, 0.f, 0.f};

  // issue tile 0
  {
    char* kl = (char*)&Ks[0][0] + w * 1024;
    char* vl = (char*)&Vs[0][0] + w * 1024;
#pragma unroll
    for (int it = 0; it < 4; it++) async16(kbase[it], kl + it * 4096);
#pragma unroll
    for (int it = 0; it < 4; it++) async16(vbase[it], vl + it * 4096);
  }

  for (int kt = 0; kt <= qt; ++kt) {
    __syncthreads();   // vmcnt drain: tile kt resident; all waves done with other buf
    if (kt < qt) {     // prefetch kt+1 into other buffer (overlaps compute below)
      const int bi = (kt + 1) & 1;
      const long ko = (long)(kt + 1) << 6;
      char* kl = (char*)&Ks[bi][0] + w * 1024;
      char* vl = (char*)&Vs[bi][0] + w * 1024;
#pragma unroll
      for (int it = 0; it < 4; it++) async16(kbase[it] + ko * 2048, kl + it * 4096);
#pragma unroll
      for (int it = 0; it < 4; it++) async16(vbase[it] + ko, vl + it * 4096);
    }
    const u16* Kb = Ks[kt & 1];
    const u16* Vb = Vs[kt & 1];

    // S = Q K^T  (D: row qi = quad*4+r, col kj = jt*16+ln)
    f4v S[4];
#pragma unroll
    for (int jt = 0; jt < 4; jt++) {
      f4v s = {};
#pragma unroll
      for (int dt = 0; dt < 4; dt++) {
        const bf8v bk = *(const bf8v*)&Kb[((jt * 4 + dt) * 64 + lane) * 8];
        s = __builtin_amdgcn_mfma_f32_16x16x32_bf16(aq[dt], bk, s, 0, 0, 0);
      }
      S[jt] = s;
    }
    const float scl = 0.08838834764831845f;  // 1/sqrt(128)
    if (kt == qt) {                          // only diagonal tile needs masking
      const int qi_loc = w * 16 + quad * 4;
#pragma unroll
      for (int jt = 0; jt < 4; jt++)
#pragma unroll
        for (int r = 0; r < 4; r++) {
          float v = S[jt][r] * scl;
          if (jt * 16 + ln > qi_loc + r) v = -1e30f;
          S[jt][r] = v;
        }
    } else {
#pragma unroll
      for (int jt = 0; jt < 4; jt++)
#pragma unroll
        for (int r = 0; r < 4; r++) S[jt][r] *= scl;
    }
    // online softmax per row r (16-lane butterflies within quad group)
#pragma unroll
    for (int r = 0; r < 4; r++) {
      float mx = fmaxf(fmaxf(S[0][r], S[1][r]), fmaxf(S[2][r], S[3][r]));
      mx = fmaxf(mx, __shfl_xor(mx, 1)); mx = fmaxf(mx, __shfl_xor(mx, 2));
      mx = fmaxf(mx, __shfl_xor(mx, 4)); mx = fmaxf(mx, __shfl_xor(mx, 8));
      const float mnew = fmaxf(m_run[r], mx);
      const float alpha = __expf(m_run[r] - mnew);
      m_run[r] = mnew;
      float ls = 0.f;
#pragma unroll
      for (int jt = 0; jt < 4; jt++) {
        const float p = __expf(S[jt][r] - mnew);
        S[jt][r] = p; ls += p;
      }
      ls += __shfl_xor(ls, 1); ls += __shfl_xor(ls, 2);
      ls += __shfl_xor(ls, 4); ls += __shfl_xor(ls, 8);
      l_run[r] = l_run[r] * alpha + ls;
#pragma unroll
      for (int nt = 0; nt < 8; nt++) O[nt][r] *= alpha;
    }
    // P transpose through per-wave LDS region (same-wave DS ops are in-order;
    // no barrier needed -> prefetch stays in flight)
    const int wbase = w * 16 * 72;
#pragma unroll
    for (int jt = 0; jt < 4; jt++)
#pragma unroll
      for (int r = 0; r < 4; r++)
        Ps[wbase + (quad * 4 + r) * 72 + jt * 16 + ln] = f2bf(S[jt][r]);
    bf8v ap[2];
#pragma unroll
    for (int k2 = 0; k2 < 2; k2++)
      ap[k2] = *(const bf8v*)&Ps[wbase + ln * 72 + k2 * 32 + quad * 8];
#pragma unroll
    for (int nt = 0; nt < 8; nt++) {
#pragma unroll
      for (int k2 = 0; k2 < 2; k2++) {
        const bf8v bv = *(const bf8v*)&Vb[((nt * 2 + k2) * 64 + lane) * 8];
        O[nt] = __builtin_amdgcn_mfma_f32_16x16x32_bf16(ap[k2], bv, O[nt], 0, 0, 0);
      }
    }
  }

  float inv[4];
#pragma unroll
  for (int r = 0; r < 4; r++) inv[r] = 1.0f / l_run[r];
  const long ob = ((long)(b * 2048 + q0 + w * 16 + quad * 4)) * 2048 + h * 128 + ln;
#pragma unroll
  for (int r = 0; r < 4; r++)
#pragma unroll
    for (int nt = 0; nt < 8; nt++)
      ao[ob + (long)r * 2048 + nt * 16] = f2bf(O[nt][r] * inv[r]);
}

// ---------------------------------------------------------------------------
extern "C" void kernel_launch(void* const* d_in, const int* in_sizes, int n_in,
                              void* d_out, int out_size, void* d_ws, size_t ws_size,
                              hipStream_t stream) {
  const float* x  = (const float*)d_in[0];
  const float* cs = (const float*)d_in[1];
  const float* sn = (const float*)d_in[2];
  const float* Wq = (const float*)d_in[3];
  const float* Wk = (const float*)d_in[4];
  const float* Wv = (const float*)d_in[5];
  const float* Wo = (const float*)d_in[6];
  float* out = (float*)d_out;

  const size_t E = 4194304;   // 2048*2048 elements
  u16* xb = (u16*)d_ws;       // [4096,2048] bf16; later aliased as aob

  const size_t need = 11 * E * sizeof(u16);   // 92.3 MB for fused path
  if (ws_size >= need) {
    u16* wqkv = xb + 2 * E;       // [6144, 2048]
    u16* qb   = wqkv + 3 * E;     // [4096, 2048]
    u16* kb   = qb + 2 * E;
    u16* vtb  = kb + 2 * E;       // [32,128,2048] V^T
    u16* aob  = xb;

    f2b_k<<<8192, 256, 0, stream>>>(x, xb);
    f2b3_k<<<12288, 256, 0, stream>>>(Wq, Wk, Wv, wqkv);
    gemm_bt<<<dim3(48, 32), 256, 0, stream>>>(xb, wqkv, qb, kb, vtb, nullptr, 3);
    rope2_k<<<32768, 256, 0, stream>>>(qb, kb, cs, sn);
    attn_k<<<dim3(32, 32), 256, 0, stream>>>(qb, kb, vtb, aob);
    f2b_k<<<4096, 256, 0, stream>>>(Wo, wqkv);
    gemm_bt<<<dim3(16, 32), 256, 0, stream>>>(aob, wqkv, nullptr, nullptr, nullptr, out, 2);
  } else {
    // fallback: per-weight conversion, 75.6 MB (known to fit)
    u16* wb  = xb + 2 * E;        // [2048,2048], reused per-W
    u16* qb  = wb + E;
    u16* kb  = qb + 2 * E;
    u16* vtb = kb + 2 * E;
    u16* aob = xb;

    f2b_k<<<8192, 256, 0, stream>>>(x, xb);
    f2b_k<<<4096, 256, 0, stream>>>(Wq, wb);
    gemm_bt<<<dim3(16, 32), 256, 0, stream>>>(xb, wb, qb, nullptr, nullptr, nullptr, 0);
    f2b_k<<<4096, 256, 0, stream>>>(Wk, wb);
    gemm_bt<<<dim3(16, 32), 256, 0, stream>>>(xb, wb, kb, nullptr, nullptr, nullptr, 0);
    f2b_k<<<4096, 256, 0, stream>>>(Wv, wb);
    gemm_bt<<<dim3(16, 32), 256, 0, stream>>>(xb, wb, vtb, nullptr, nullptr, nullptr, 1);
    rope2_k<<<32768, 256, 0, stream>>>(qb, kb, cs, sn);
    attn_k<<<dim3(32, 32), 256, 0, stream>>>(qb, kb, vtb, aob);
    f2b_k<<<4096, 256, 0, stream>>>(Wo, wb);
    gemm_bt<<<dim3(16, 32), 256, 0, stream>>>(aob, wb, nullptr, nullptr, nullptr, out, 2);
  }
}

// Round 5
// 594.299 us; speedup vs baseline: 1.1550x; 1.1550x over previous
//
#include <hip/hip_runtime.h>

typedef unsigned short u16;
typedef __attribute__((ext_vector_type(8))) short bf8v;   // 8 bf16 = 4 VGPRs
typedef __attribute__((ext_vector_type(4))) float f4v;

#define DEV static __device__ __forceinline__

DEV float bf2f(u16 u){ unsigned x = ((unsigned)u) << 16; float f; __builtin_memcpy(&f, &x, 4); return f; }
DEV u16 f2bf(float f){ unsigned x; __builtin_memcpy(&x, &f, 4); x += 0x7fff + ((x >> 16) & 1); return (u16)(x >> 16); }

DEV void async16(const void* g, void* l){
  __builtin_amdgcn_global_load_lds((const __attribute__((address_space(1))) unsigned*)g,
                                   (__attribute__((address_space(3))) unsigned*)l, 16, 0, 0);
}

// ---------------------------------------------------------------------------
// fp32 -> bf16 conversion, 4 elements/thread.
// ---------------------------------------------------------------------------
__global__ __launch_bounds__(256) void f2b_k(const float* __restrict__ src,
                                             u16* __restrict__ dst)
{
  const long i = ((long)blockIdx.x * 256 + threadIdx.x) * 4;
  const float4 v = *(const float4*)(src + i);
  ushort4 o;
  o.x = f2bf(v.x); o.y = f2bf(v.y); o.z = f2bf(v.z); o.w = f2bf(v.w);
  *(ushort4*)(dst + i) = o;
}

// three weights -> one contiguous [6144,2048] bf16 buffer
__global__ __launch_bounds__(256) void f2b3_k(const float* __restrict__ a,
                                              const float* __restrict__ b,
                                              const float* __restrict__ c,
                                              u16* __restrict__ dst)
{
  const int bx = blockIdx.x;                       // 0..12287
  const float* s = bx < 4096 ? a : (bx < 8192 ? b : c);
  const long soff = ((long)(bx & 4095) * 256 + threadIdx.x) * 4;
  const long doff = ((long)bx * 256 + threadIdx.x) * 4;
  const float4 v = *(const float4*)(s + soff);
  ushort4 o;
  o.x = f2bf(v.x); o.y = f2bf(v.y); o.z = f2bf(v.z); o.w = f2bf(v.w);
  *(ushort4*)(dst + doff) = o;
}

// ---------------------------------------------------------------------------
// GEMM: C[M,N] = A[M,K] * B[N,K]^T, bf16 in, fp32 accum. K=2048.
// 128x128 tile, BK=64 (2 MFMA sub-blocks per barrier pair), 4 waves (2x2).
// LDS chunk p (16B) holds row=(G>>3)*64+((G>>1)&3)*16+(p&15) (G=p>>6),
// col=((G&1)*32+((p>>4)&3)*8; frag reads are chunk=((wh*4+i)*2+s)*64+lane
// -> stride-1 b128, conflict-free. 2-barrier classic loop (m97 pattern);
// explicit dbuf measured WORSE (round 4) -- do not re-add.
// mode 0: C0 bf16 row-major [M,2048]
// mode 1: C0 <- V-transpose [bh,d,s]
// mode 2: Cf fp32 row-major (final output)
// mode 3: fused QKV (N=6144): sec0->C0 (q), sec1->C1 (k), sec2->C2 (v transp)
// ---------------------------------------------------------------------------
constexpr int KDIM = 2048;

__global__ __launch_bounds__(256, 3) void gemm_bt(const u16* __restrict__ A,
                                                  const u16* __restrict__ B,
                                                  u16* __restrict__ C0,
                                                  u16* __restrict__ C1,
                                                  u16* __restrict__ C2,
                                                  float* __restrict__ Cf, int mode)
{
  __shared__ __align__(16) u16 As[128 * 64];   // 16 KB
  __shared__ __align__(16) u16 Bs[128 * 64];   // 16 KB
  const int tid = threadIdx.x;
  const int w = tid >> 6, lane = tid & 63;
  const int ln = lane & 15, quad = lane >> 4;
  const int wh = w >> 1, wn1 = w & 1;
  const int wm = wh << 6, wn = wn1 << 6;
  const long m0 = (long)blockIdx.y << 7, n0 = (long)blockIdx.x << 7;

  f4v acc[4][4] = {};

  // staging: per-thread global base; chunk p = it*256+tid, G=p>>6=it*4+w
  const int colb = (w & 1) * 32 + ((tid >> 4) & 3) * 8;
  const u16* gA = A + (m0 + (tid & 15)) * (long)KDIM + colb;
  const u16* gB = B + (n0 + (tid & 15)) * (long)KDIM + colb;
  int rowadd[4];
#pragma unroll
  for (int it = 0; it < 4; ++it) {
    const int G = it * 4 + w;
    rowadd[it] = (G >> 3) * 64 + ((G >> 1) & 3) * 16;
  }

  for (int k0 = 0; k0 < KDIM; k0 += 64) {
    __syncthreads();                           // all waves done reading LDS
#pragma unroll
    for (int it = 0; it < 4; ++it)
      async16(gA + (long)rowadd[it] * KDIM + k0, (char*)As + it * 4096 + w * 1024);
#pragma unroll
    for (int it = 0; it < 4; ++it)
      async16(gB + (long)rowadd[it] * KDIM + k0, (char*)Bs + it * 4096 + w * 1024);
    __syncthreads();                           // drain: tile resident
#pragma unroll
    for (int s = 0; s < 2; ++s) {
      bf8v a[4], b[4];
#pragma unroll
      for (int i = 0; i < 4; i++) a[i] = *(const bf8v*)&As[(((wh * 4 + i) * 2 + s) * 64 + lane) * 8];
#pragma unroll
      for (int j = 0; j < 4; j++) b[j] = *(const bf8v*)&Bs[(((wn1 * 4 + j) * 2 + s) * 64 + lane) * 8];
#pragma unroll
      for (int i = 0; i < 4; i++)
#pragma unroll
        for (int j = 0; j < 4; j++)
          acc[i][j] = __builtin_amdgcn_mfma_f32_16x16x32_bf16(a[i], b[j], acc[i][j], 0, 0, 0);
    }
  }

  // epilogue: D row = quad*4+reg (m), col = ln (n)
#pragma unroll
  for (int i = 0; i < 4; i++) {
    const long mrow = m0 + wm + i * 16 + quad * 4;
#pragma unroll
    for (int j = 0; j < 4; j++) {
      const long ncol = n0 + wn + j * 16 + ln;
#pragma unroll
      for (int r = 0; r < 4; r++) {
        const float fv = acc[i][j][r];
        const long m = mrow + r;
        if (mode == 0) {
          C0[m * 2048 + ncol] = f2bf(fv);
        } else if (mode == 2) {
          Cf[m * 2048 + ncol] = fv;
        } else if (mode == 1) {
          const long s = m & 2047, bb = m >> 11;
          const long hh = ncol >> 7, dc = ncol & 127;
          C0[((bb * 16 + hh) * 128 + dc) * 2048 + s] = f2bf(fv);
        } else {             // mode 3: fused QKV, sec uniform per block
          const int sec = (int)(n0 >> 11);
          const long nc = ncol & 2047;
          if (sec == 0)      C0[m * 2048 + nc] = f2bf(fv);
          else if (sec == 1) C1[m * 2048 + nc] = f2bf(fv);
          else {
            const long s = m & 2047, bb = m >> 11;
            const long hh = nc >> 7, dc = nc & 127;
            C2[((bb * 16 + hh) * 128 + dc) * 2048 + s] = f2bf(fv);
          }
        }
      }
    }
  }
}

// ---------------------------------------------------------------------------
// RoPE in place on q and k (bf16 [4096, 16*128]); cos/sin fp32 [2048,128].
// ---------------------------------------------------------------------------
__global__ __launch_bounds__(256) void rope2_k(u16* __restrict__ qb,
                                               u16* __restrict__ kb,
                                               const float* __restrict__ cs,
                                               const float* __restrict__ sn)
{
  const long idx = (long)blockIdx.x * 256 + threadIdx.x;   // [0, 2*4194304)
  u16* t = (idx >= 4194304) ? kb : qb;
  const long i2 = idx & 4194303;
  const long m = i2 >> 10;
  const int rest = (int)(i2 & 1023);
  const int h = rest >> 6, d = rest & 63;
  const int s = (int)(m & 2047);
  const long base = m * 2048 + h * 128 + d;
  const float a  = bf2f(t[base]), b = bf2f(t[base + 64]);
  const float c1 = cs[s * 128 + d],      s1 = sn[s * 128 + d];
  const float c2 = cs[s * 128 + d + 64], s2 = sn[s * 128 + d + 64];
  t[base]      = f2bf(a * c1 - b * s1);
  t[base + 64] = f2bf(b * c2 + a * s2);
}

// ---------------------------------------------------------------------------
// Flash attention (causal). Block = 4 waves; wave w owns 16 q-rows.
// K-block = 128 cols per barrier pair (two 64-col subs sharing one softmax
// pass and one O-rescale). LDS: Ks 32 KB (2 subs) + Vs 32 KB + Ps 9 KB.
// Identity chunk layouts (conflict-free stride-1 b128 reads):
//   K sub chunk q: row kj=(q>>8)*16+(q&15), d=((q>>6)&3)*32+((q>>4)&3)*8
//   V sub chunk q: d=((q>>7)&7)*16+(q&15), kc=((q>>6)&1)*32+((q>>4)&3)*8
// qt reversed so longest blocks dispatch first.
// ---------------------------------------------------------------------------
__global__ __launch_bounds__(256) void attn_k(const u16* __restrict__ q,
                                              const u16* __restrict__ k,
                                              const u16* __restrict__ vt,
                                              u16* __restrict__ ao)
{
  __shared__ __align__(16) u16 Ks[128 * 128];     // 32 KB: sub s at elem s*8192
  __shared__ __align__(16) u16 Vs[128 * 128];     // 32 KB: sub s at elem s*8192
  __shared__ __align__(16) u16 Ps[4 * 16 * 72];   // per-wave P, stride 72
  const int qt = 31 - blockIdx.x;
  const int bh = blockIdx.y;
  const int b = bh >> 4, h = bh & 15;
  const int tid = threadIdx.x;
  const int w = tid >> 6, lane = tid & 63;
  const int ln = lane & 15, quad = lane >> 4;
  const int q0 = qt << 6;

  // staging bases (register-light: derive per-it offsets from tid)
  const u16* kb0 = k + ((long)(b * 2048 + (tid & 15))) * 2048 + h * 128
                     + ((tid >> 6) & 3) * 32 + ((tid >> 4) & 3) * 8;
  const u16* vb0 = vt + ((long)(bh * 128 + (tid & 15))) * 2048
                      + ((tid >> 6) & 1) * 32 + ((tid >> 4) & 3) * 8;
  const int tb = tid >> 7;   // 0/1

  // Q fragments (A operand: m = ln, k = quad*8+j per 32-chunk)
  bf8v aq[4];
  {
    const u16* qp = q + ((long)(b * 2048 + q0 + w * 16 + ln)) * 2048 + h * 128;
#pragma unroll
    for (int dt = 0; dt < 4; ++dt) aq[dt] = *(const bf8v*)(qp + dt * 32 + quad * 8);
  }
  f4v O[8] = {};
  float m_run[4] = {-1e30f, -1e30f, -1e30f, -1e30f};
  float l_run[4] = {0.f, 0.f, 0.f, 0.f};

  const int nktp = qt >> 1;
  for (int ktp = 0; ktp <= nktp; ++ktp) {
    const int k0s = ktp << 7;
    const bool has1 = (2 * ktp + 1) <= qt;   // wave-uniform

    __syncthreads();   // all waves done reading previous tiles
    // stage K: chunk p = it*256+tid; sub=it>>2, jt=it&3 (row add uniform per it)
#pragma unroll
    for (int it = 0; it < 8; ++it) {
      const int rowu = (it >> 2) * 64 + (it & 3) * 16;
      async16(kb0 + (long)(k0s + rowu) * 2048, (char*)Ks + it * 4096 + w * 1024);
    }
    // stage V^T: g = 2*it+tb; d-add = (g&7)*16 rows; k-add = (g>>3)*64 + k0s
#pragma unroll
    for (int it = 0; it < 8; ++it) {
      const int g = 2 * it + tb;
      const long off = (long)((g & 7) * 16) * 2048 + (g >> 3) * 64 + k0s;
      async16(vb0 + off, (char*)Vs + it * 4096 + w * 1024);
    }
    __syncthreads();   // drain: both subs resident

    // S = Q K^T over 8 jt tiles (D: row qi = quad*4+r, col = jt*16+ln local)
    f4v S[8];
#pragma unroll
    for (int jt = 0; jt < 8; jt++) {
      if (jt >= 4 && !has1) { S[jt] = (f4v){-1e30f, -1e30f, -1e30f, -1e30f}; continue; }
      const int sub = jt >> 2, jl = jt & 3;
      f4v s = {};
#pragma unroll
      for (int dt = 0; dt < 4; dt++) {
        const bf8v bk = *(const bf8v*)&Ks[(sub * 1024 + (jl * 4 + dt) * 64 + lane) * 8];
        s = __builtin_amdgcn_mfma_f32_16x16x32_bf16(aq[dt], bk, s, 0, 0, 0);
      }
      S[jt] = s;
    }
    const float scl = 0.08838834764831845f;  // 1/sqrt(128)
    if (ktp == nktp) {                       // only last iter can touch diagonal
#pragma unroll
      for (int jt = 0; jt < 8; jt++) {
        const int dcol = k0s - q0 + (jt >> 2) * 64 + (jt & 3) * 16 + ln;
        const int qi_loc = w * 16 + quad * 4;
#pragma unroll
        for (int r = 0; r < 4; r++) {
          float v = S[jt][r] * scl;
          if (dcol > qi_loc + r) v = -1e30f;
          S[jt][r] = v;
        }
      }
    } else {
#pragma unroll
      for (int jt = 0; jt < 8; jt++)
#pragma unroll
        for (int r = 0; r < 4; r++) S[jt][r] *= scl;
    }
    // online softmax per row r (16-lane butterflies within quad group)
#pragma unroll
    for (int r = 0; r < 4; r++) {
      float mx = S[0][r];
#pragma unroll
      for (int jt = 1; jt < 8; jt++) mx = fmaxf(mx, S[jt][r]);
      mx = fmaxf(mx, __shfl_xor(mx, 1)); mx = fmaxf(mx, __shfl_xor(mx, 2));
      mx = fmaxf(mx, __shfl_xor(mx, 4)); mx = fmaxf(mx, __shfl_xor(mx, 8));
      const float mnew = fmaxf(m_run[r], mx);
      const float alpha = __expf(m_run[r] - mnew);
      m_run[r] = mnew;
      float ls = 0.f;
#pragma unroll
      for (int jt = 0; jt < 8; jt++) {
        const float p = __expf(S[jt][r] - mnew);
        S[jt][r] = p; ls += p;
      }
      ls += __shfl_xor(ls, 1); ls += __shfl_xor(ls, 2);
      ls += __shfl_xor(ls, 4); ls += __shfl_xor(ls, 8);
      l_run[r] = l_run[r] * alpha + ls;
#pragma unroll
      for (int nt = 0; nt < 8; nt++) O[nt][r] *= alpha;
    }
    // PV per sub: P transpose through per-wave LDS region (same-wave DS ops
    // are in-order -> no barrier; Ps region reused for sub1 after sub0 reads)
    const int wbase = w * 16 * 72;
#pragma unroll
    for (int sub = 0; sub < 2; ++sub) {
      if (sub == 1 && !has1) break;
#pragma unroll
      for (int jl = 0; jl < 4; jl++)
#pragma unroll
        for (int r = 0; r < 4; r++)
          Ps[wbase + (quad * 4 + r) * 72 + jl * 16 + ln] = f2bf(S[sub * 4 + jl][r]);
      bf8v ap[2];
#pragma unroll
      for (int k2 = 0; k2 < 2; k2++)
        ap[k2] = *(const bf8v*)&Ps[wbase + ln * 72 + k2 * 32 + quad * 8];
#pragma unroll
      for (int nt = 0; nt < 8; nt++) {
#pragma unroll
        for (int k2 = 0; k2 < 2; k2++) {
          const bf8v bv = *(const bf8v*)&Vs[(sub * 1024 + (nt * 2 + k2) * 64 + lane) * 8];
          O[nt] = __builtin_amdgcn_mfma_f32_16x16x32_bf16(ap[k2], bv, O[nt], 0, 0, 0);
        }
      }
    }
  }

  float inv[4];
#pragma unroll
  for (int r = 0; r < 4; r++) inv[r] = 1.0f / l_run[r];
  const long ob = ((long)(b * 2048 + q0 + w * 16 + quad * 4)) * 2048 + h * 128 + ln;
#pragma unroll
  for (int r = 0; r < 4; r++)
#pragma unroll
    for (int nt = 0; nt < 8; nt++)
      ao[ob + (long)r * 2048 + nt * 16] = f2bf(O[nt][r] * inv[r]);
}

// ---------------------------------------------------------------------------
extern "C" void kernel_launch(void* const* d_in, const int* in_sizes, int n_in,
                              void* d_out, int out_size, void* d_ws, size_t ws_size,
                              hipStream_t stream) {
  const float* x  = (const float*)d_in[0];
  const float* cs = (const float*)d_in[1];
  const float* sn = (const float*)d_in[2];
  const float* Wq = (const float*)d_in[3];
  const float* Wk = (const float*)d_in[4];
  const float* Wv = (const float*)d_in[5];
  const float* Wo = (const float*)d_in[6];
  float* out = (float*)d_out;

  const size_t E = 4194304;   // 2048*2048 elements
  u16* xb = (u16*)d_ws;       // [4096,2048] bf16; later aliased as aob

  const size_t need = 11 * E * sizeof(u16);   // 92.3 MB for fused path
  if (ws_size >= need) {
    u16* wqkv = xb + 2 * E;       // [6144, 2048]
    u16* qb   = wqkv + 3 * E;     // [4096, 2048]
    u16* kb   = qb + 2 * E;
    u16* vtb  = kb + 2 * E;       // [32,128,2048] V^T
    u16* aob  = xb;

    f2b_k<<<8192, 256, 0, stream>>>(x, xb);
    f2b3_k<<<12288, 256, 0, stream>>>(Wq, Wk, Wv, wqkv);
    gemm_bt<<<dim3(48, 32), 256, 0, stream>>>(xb, wqkv, qb, kb, vtb, nullptr, 3);
    rope2_k<<<32768, 256, 0, stream>>>(qb, kb, cs, sn);
    attn_k<<<dim3(32, 32), 256, 0, stream>>>(qb, kb, vtb, aob);
    f2b_k<<<4096, 256, 0, stream>>>(Wo, wqkv);
    gemm_bt<<<dim3(16, 32), 256, 0, stream>>>(aob, wqkv, nullptr, nullptr, nullptr, out, 2);
  } else {
    // fallback: per-weight conversion, 75.6 MB (known to fit)
    u16* wb  = xb + 2 * E;        // [2048,2048], reused per-W
    u16* qb  = wb + E;
    u16* kb  = qb + 2 * E;
    u16* vtb = kb + 2 * E;
    u16* aob = xb;

    f2b_k<<<8192, 256, 0, stream>>>(x, xb);
    f2b_k<<<4096, 256, 0, stream>>>(Wq, wb);
    gemm_bt<<<dim3(16, 32), 256, 0, stream>>>(xb, wb, qb, nullptr, nullptr, nullptr, 0);
    f2b_k<<<4096, 256, 0, stream>>>(Wk, wb);
    gemm_bt<<<dim3(16, 32), 256, 0, stream>>>(xb, wb, kb, nullptr, nullptr, nullptr, 0);
    f2b_k<<<4096, 256, 0, stream>>>(Wv, wb);
    gemm_bt<<<dim3(16, 32), 256, 0, stream>>>(xb, wb, vtb, nullptr, nullptr, nullptr, 1);
    rope2_k<<<32768, 256, 0, stream>>>(qb, kb, cs, sn);
    attn_k<<<dim3(32, 32), 256, 0, stream>>>(qb, kb, vtb, aob);
    f2b_k<<<4096, 256, 0, stream>>>(Wo, wb);
    gemm_bt<<<dim3(16, 32), 256, 0, stream>>>(aob, wb, nullptr, nullptr, nullptr, out, 2);
  }
}